// Round 5
// baseline (45.666 us; speedup 1.0000x reference)
//
#include <hip/hip_runtime.h>
#include <math.h>

#define B_ 64
#define S_ 24
#define E_ 128
#define G_ 256
#define N_ (B_ * S_)      // 1536
#define Km_ 100
#define Kch_ 200
#define Ko_ 50
#define Kp_ 50
#define Kc_ 30
#define TOTK_ 435         // 100+200+50+50+1+30+4

#define Vm_ 1000
#define Vch_ 3000
#define Vo_ 500
#define Vp_ 1500
#define Vl_ 700
#define Vc_ 2000
#define TOTROWS_ 8817     // sum of all table rows

// rowmean buffer segment offsets (floats, in d_ws)
#define OFF_MED 0
#define OFF_CHART 1000
#define OFF_OUT 4000
#define OFF_PROC 4500
#define OFF_LAB 6000
#define OFF_COND 6700
#define OFF_GEN 8700
#define OFF_ETH 8702
#define OFF_INS 8712
#define OFF_AGE 8717
// ws layout after rm[8817]:
#define OFF_CTR 8824      // int counter, reset by kernel A
#define OFF_PART 8832     // part[TOTK_][32] floats (byte off 35328, 16B-aligned)

#define NCHUNK_ 32        // n-chunks per big table
#define CHUNK_N_ 48       // 1536 / 32
#define NBLK_B_ 129       // 128 table-chunk blocks + 1 small block
#define NTHR_ 512

#define NBLKA_ROWS_ ((TOTROWS_ + 7) / 8)   // 1103 row blocks (8 waves/block)
#define NBLKA_PF_ 64                        // 8 slices x 8 XCD copies

__device__ __forceinline__ int clampi(int v, int hi) {
    return v < 0 ? 0 : (v > hi ? hi : v);
}

// ---------------------------------------------------------------------------
// Weight prefetch: 64 blocks; slice = (pfid>>3). 8 consecutive bids per slice
// round-robin all 8 XCDs, so every XCD's private L2 receives ALL 740KB of
// head weights before kernel B's winner-block head reads them.
// ---------------------------------------------------------------------------
__device__ __forceinline__ void prefetch_body(
    int part, int t,
    const float* __restrict__ projW, const float* __restrict__ W1,
    const float* __restrict__ W2,   const float* __restrict__ fc1W)
{
    const float* arrs[4] = {projW, W1, W2, fc1W};
    const int n4s[4] = {TOTK_ * E_ / 4, E_ * G_ / 4, G_ * G_ / 4, G_ * (G_/2) / 4};
    float acc = 0.f;
    #pragma unroll
    for (int a = 0; a < 4; ++a) {
        const float4* p = (const float4*)arrs[a];
        const int n4 = n4s[a];
        const int chunk = (n4 + 7) >> 3;
        const int s0 = part * chunk;
        const int s1 = (s0 + chunk < n4) ? s0 + chunk : n4;
        for (int i = s0 + t; i < s1; i += NTHR_) {
            float4 v = p[i];
            acc += v.x + v.y + v.z + v.w;
        }
    }
    asm volatile("" : : "v"(acc));   // keep loads live (no DCE)
}

// ---------------------------------------------------------------------------
// Kernel A: rowmeans (one wave per embedding row) + weight L2 prefetch.
// Block 0 also resets the completion counter for kernel B.
// ---------------------------------------------------------------------------
__global__ __launch_bounds__(NTHR_) void rowmeans_kernel(
    const float* __restrict__ medE, const float* __restrict__ chartE,
    const float* __restrict__ outE, const float* __restrict__ procE,
    const float* __restrict__ labE, const float* __restrict__ condE,
    const float* __restrict__ genE, const float* __restrict__ ethE,
    const float* __restrict__ insE, const float* __restrict__ ageE,
    const float* __restrict__ projW, const float* __restrict__ W1,
    const float* __restrict__ W2,   const float* __restrict__ fc1W,
    float* __restrict__ rm, int* __restrict__ ctr)
{
    if (blockIdx.x == 0 && threadIdx.x == 0) *ctr = 0;

    if (blockIdx.x >= NBLKA_ROWS_) {
        prefetch_body((blockIdx.x - NBLKA_ROWS_) >> 3, threadIdx.x,
                      projW, W1, W2, fc1W);
        return;
    }

    int row = blockIdx.x * (NTHR_ / 64) + (threadIdx.x >> 6);
    int lane = threadIdx.x & 63;
    if (row >= TOTROWS_) return;

    const float* src;
    int r = row;
    if (r < Vm_)                  { src = medE; }
    else if ((r -= Vm_)  < Vch_)  { src = chartE; }
    else if ((r -= Vch_) < Vo_)   { src = outE; }
    else if ((r -= Vo_)  < Vp_)   { src = procE; }
    else if ((r -= Vp_)  < Vl_)   { src = labE; }
    else if ((r -= Vl_)  < Vc_)   { src = condE; }
    else if ((r -= Vc_)  < 2)     { src = genE; }
    else if ((r -= 2)    < 10)    { src = ethE; }
    else if ((r -= 10)   < 5)     { src = insE; }
    else                          { r -= 5; src = ageE; }

    float2 v = *reinterpret_cast<const float2*>(src + (size_t)r * E_ + lane * 2);
    float s = v.x + v.y;
    #pragma unroll
    for (int off = 32; off > 0; off >>= 1) s += __shfl_down(s, off, 64);
    if (lane == 0) rm[row] = s * (1.0f / E_);
}

// ---------------------------------------------------------------------------
// Coalesced per-table chunk colsum: threads map to (row-in-group, column) so
// idx loads are contiguous; per-column partial -> part[c][chunk]. Gather
// loops fully unrolled -> many independent idx->rm chains in flight.
// ---------------------------------------------------------------------------
template<int K, int RPI, int CBASE, int RMBASE, int VMAX>
__device__ __forceinline__ void table_chunk(
    const int* __restrict__ idx, const float* __restrict__ rm,
    float* __restrict__ part, int p, int t, float* __restrict__ lds)
{
    constexpr int ACT = K * RPI;
    float acc = 0.0f;
    if (t < ACT) {
        const int kk = t % K;
        const int nr = t / K;
        const int n0 = p * CHUNK_N_;
        #pragma unroll
        for (int i = 0; i < (CHUNK_N_ + RPI - 1) / RPI; ++i) {
            int n = n0 + nr + i * RPI;
            if (nr + i * RPI < CHUNK_N_) {
                int ix = clampi(idx[n * K + kk], VMAX);
                acc += rm[RMBASE + ix];
            }
        }
    }
    lds[t] = acc;
    __syncthreads();
    if (t < K) {
        float s = lds[t];
        #pragma unroll
        for (int r = 1; r < RPI; ++r) s += lds[r * K + t];
        part[(CBASE + t) * NCHUNK_ + p] = s;   // raw sum; scaled in head
    }
}

// ---------------------------------------------------------------------------
// Head: sums the 32 partials per column (fixed order), scales, then the
// 4-stage MLP chain 8-way k-split. Entropy weight over identical rows == 1/N.
// ---------------------------------------------------------------------------
__device__ void head_body(
    const float* __restrict__ part,
    const float* __restrict__ projW, const float* __restrict__ projb,
    const float* __restrict__ W1, const float* __restrict__ b1,
    const float* __restrict__ W2, const float* __restrict__ b2,
    const float* __restrict__ fc1W, const float* __restrict__ fc1b,
    const float* __restrict__ fc2W, const float* __restrict__ fc2b,
    float* __restrict__ outp)
{
    __shared__ float sm[TOTK_];
    __shared__ float xbar[E_];
    __shared__ float h1s[G_];
    __shared__ float h2s[G_];
    __shared__ float fsh[G_ / 2];
    __shared__ float4 part4[8][64];
    __shared__ float2 part2[8][64];
    __shared__ float hred[8];
    __shared__ float oval;

    const int t = threadIdx.x;
    const int lane = t & 63;
    const int oc = t >> 6;      // wave-group 0..7

    // ---- partial-sum stage: sm[k] = scale * sum_p part[k][p]
    if (t < TOTK_) {
        const float4* pp = (const float4*)(part + t * NCHUNK_);
        float s;
        if (t < 400) {
            s = 0.f;
            #pragma unroll
            for (int j = 0; j < NCHUNK_ / 4; ++j) {
                float4 v = pp[j];
                s += (v.x + v.y) + (v.z + v.w);
            }
            s *= (1.0f / N_);
        } else if (t == 400) {
            s = part[t * NCHUNK_] * (1.0f / N_);
        } else {
            s = part[t * NCHUNK_] * (1.0f / B_);
        }
        sm[t] = s;
    }
    __syncthreads();

    // ---- xbar[128] = sm[435] @ projW[435,128] + projb : float2, 8-way
    {
        const float2* Wp = (const float2*)projW;   // [435][64]
        const int k0 = (TOTK_ * oc) >> 3;
        const int k1 = (TOTK_ * (oc + 1)) >> 3;
        float2 acc = {0.f, 0.f};
        #pragma unroll 8
        for (int k = k0; k < k1; ++k) {
            float s = sm[k];
            float2 w = Wp[k * 64 + lane];
            acc.x += s * w.x; acc.y += s * w.y;
        }
        part2[oc][lane] = acc;
        __syncthreads();
        if (t < 64) {
            float2 a = part2[0][t];
            #pragma unroll
            for (int j = 1; j < 8; ++j) { a.x += part2[j][t].x; a.y += part2[j][t].y; }
            xbar[2 * t]     = a.x + projb[2 * t];
            xbar[2 * t + 1] = a.y + projb[2 * t + 1];
        }
        __syncthreads();
    }

    // ---- h1[256] = relu(xbar @ W1[128,256] + b1) * (1/N) : float4, 8-way
    {
        const float4* Wp = (const float4*)W1;      // [128][64]
        const int k0 = oc * 16, k1 = k0 + 16;
        float4 acc = {0.f, 0.f, 0.f, 0.f};
        #pragma unroll 8
        for (int k = k0; k < k1; ++k) {
            float s = xbar[k];
            float4 w = Wp[k * 64 + lane];
            acc.x += s * w.x; acc.y += s * w.y; acc.z += s * w.z; acc.w += s * w.w;
        }
        part4[oc][lane] = acc;
        __syncthreads();
        if (t < 64) {
            float4 a = part4[0][t];
            #pragma unroll
            for (int j = 1; j < 8; ++j) {
                float4 p = part4[j][t];
                a.x += p.x; a.y += p.y; a.z += p.z; a.w += p.w;
            }
            float4 bb = ((const float4*)b1)[t];
            h1s[4 * t]     = fmaxf(a.x + bb.x, 0.f) * (1.0f / N_);
            h1s[4 * t + 1] = fmaxf(a.y + bb.y, 0.f) * (1.0f / N_);
            h1s[4 * t + 2] = fmaxf(a.z + bb.z, 0.f) * (1.0f / N_);
            h1s[4 * t + 3] = fmaxf(a.w + bb.w, 0.f) * (1.0f / N_);
        }
        __syncthreads();
    }

    // ---- h2[256] = h1 @ W2[256,256] + b2 : float4, 8-way
    {
        const float4* Wp = (const float4*)W2;      // [256][64]
        const int k0 = oc * 32, k1 = k0 + 32;
        float4 acc = {0.f, 0.f, 0.f, 0.f};
        #pragma unroll 8
        for (int k = k0; k < k1; ++k) {
            float s = h1s[k];
            float4 w = Wp[k * 64 + lane];
            acc.x += s * w.x; acc.y += s * w.y; acc.z += s * w.z; acc.w += s * w.w;
        }
        part4[oc][lane] = acc;
        __syncthreads();
        if (t < 64) {
            float4 a = part4[0][t];
            #pragma unroll
            for (int j = 1; j < 8; ++j) {
                float4 p = part4[j][t];
                a.x += p.x; a.y += p.y; a.z += p.z; a.w += p.w;
            }
            float4 bb = ((const float4*)b2)[t];
            h2s[4 * t]     = a.x + bb.x;
            h2s[4 * t + 1] = a.y + bb.y;
            h2s[4 * t + 2] = a.z + bb.z;
            h2s[4 * t + 3] = a.w + bb.w;
        }
        __syncthreads();
    }

    // ---- f[128] = relu(h2 @ fc1W[256,128] + fc1b) : float2, 8-way
    {
        const float2* Wp = (const float2*)fc1W;    // [256][64]
        const int k0 = oc * 32, k1 = k0 + 32;
        float2 acc = {0.f, 0.f};
        #pragma unroll 8
        for (int k = k0; k < k1; ++k) {
            float s = h2s[k];
            float2 w = Wp[k * 64 + lane];
            acc.x += s * w.x; acc.y += s * w.y;
        }
        part2[oc][lane] = acc;
        __syncthreads();
        if (t < 64) {
            float2 a = part2[0][t];
            #pragma unroll
            for (int j = 1; j < 8; ++j) { a.x += part2[j][t].x; a.y += part2[j][t].y; }
            fsh[2 * t]     = fmaxf(a.x + fc1b[2 * t], 0.f);
            fsh[2 * t + 1] = fmaxf(a.y + fc1b[2 * t + 1], 0.f);
        }
        __syncthreads();
    }

    // ---- o = f . fc2_W + fc2_b ; write outputs
    {
        float p = (t < G_ / 2) ? fsh[t] * fc2W[t] : 0.f;
        #pragma unroll
        for (int off = 32; off > 0; off >>= 1) p += __shfl_down(p, off, 64);
        if (lane == 0) hred[oc] = p;
        __syncthreads();
        if (t == 0) {
            float o = fc2b[0];
            #pragma unroll
            for (int j = 0; j < 8; ++j) o += hred[j];
            oval = o;
        }
        __syncthreads();
        const float o = oval;
        const float sig = 1.0f / (1.0f + expf(-o));
        if (t < B_)            outp[t] = sig;   // output 0: sigmoid(o)
        else if (t < 2 * B_)   outp[t] = o;     // output 1: o
    }
}

// ---------------------------------------------------------------------------
// Kernel B: 129 blocks. Blocks 0..127 = (table = bid/32, chunk = bid%32) with
// coalesced idx loads; block 128 = lab/conds/demo via wave reductions. The
// last block to finish (counter) runs the head (rocPRIM last-block pattern);
// its weight reads hit the L2 copies planted by kernel A.
// ---------------------------------------------------------------------------
__global__ __launch_bounds__(NTHR_) void colsum_head_kernel(
    const int* __restrict__ meds, const int* __restrict__ chart,
    const int* __restrict__ outv, const int* __restrict__ proc,
    const int* __restrict__ lab,  const int* __restrict__ conds,
    const int* __restrict__ demo,
    const float* __restrict__ rm, float* __restrict__ part, int* __restrict__ ctr,
    const float* __restrict__ projW, const float* __restrict__ projb,
    const float* __restrict__ W1, const float* __restrict__ b1,
    const float* __restrict__ W2, const float* __restrict__ b2,
    const float* __restrict__ fc1W, const float* __restrict__ fc1b,
    const float* __restrict__ fc2W, const float* __restrict__ fc2b,
    float* __restrict__ outp)
{
    __shared__ float lds_red[NTHR_];
    __shared__ int s_old;

    const int t = threadIdx.x;
    const int bid = blockIdx.x;

    if (bid < 128) {
        const int table = bid >> 5;
        const int p = bid & 31;
        if (table == 0)      table_chunk<Km_, 5, 0,   OFF_MED,  Vm_ -1>(meds,  rm, part, p, t, lds_red);
        else if (table == 1) table_chunk<Kch_,2, 100, OFF_CHART,Vch_-1>(chart, rm, part, p, t, lds_red);
        else if (table == 2) table_chunk<Ko_, 10,300, OFF_OUT,  Vo_ -1>(outv,  rm, part, p, t, lds_red);
        else                 table_chunk<Kp_, 10,350, OFF_PROC, Vp_ -1>(proc,  rm, part, p, t, lds_red);
    } else {
        // small block: 35 columns (lab, conds x30, demo x4), one per wave slot
        const int lane = t & 63;
        const int w = t >> 6;
        for (int j = w; j < 35; j += 8) {
            float s = 0.0f;
            if (j == 0) {
                #pragma unroll
                for (int i = 0; i < 24; ++i)
                    s += rm[OFF_LAB + clampi(lab[lane + 64 * i], Vl_ - 1)];
            } else if (j < 31) {
                int kk = j - 1;
                s = rm[OFF_COND + clampi(conds[lane * Kc_ + kk], Vc_ - 1)];
            } else {
                int jj = j - 31;
                int base = (jj == 0) ? OFF_GEN : (jj == 1) ? OFF_ETH :
                           (jj == 2) ? OFF_INS : OFF_AGE;
                s = rm[base + demo[lane * 4 + jj]];
            }
            #pragma unroll
            for (int off = 32; off > 0; off >>= 1) s += __shfl_down(s, off, 64);
            if (lane == 0) part[(400 + j) * NCHUNK_] = s;
        }
    }

    // last-block-done: winner runs the head
    __threadfence();
    __syncthreads();
    if (t == 0) s_old = atomicAdd(ctr, 1);
    __syncthreads();
    if (s_old == NBLK_B_ - 1) {
        __threadfence();
        head_body(part, projW, projb, W1, b1, W2, b2,
                  fc1W, fc1b, fc2W, fc2b, outp);
    }
}

// ---------------------------------------------------------------------------
extern "C" void kernel_launch(void* const* d_in, const int* in_sizes, int n_in,
                              void* d_out, int out_size, void* d_ws, size_t ws_size,
                              hipStream_t stream) {
    const int* meds  = (const int*)d_in[0];
    const int* chart = (const int*)d_in[1];
    const int* outv  = (const int*)d_in[2];
    const int* proc  = (const int*)d_in[3];
    const int* lab   = (const int*)d_in[4];
    const int* conds = (const int*)d_in[5];
    const int* demo  = (const int*)d_in[6];
    const float* medE   = (const float*)d_in[7];
    const float* chartE = (const float*)d_in[8];
    const float* outE   = (const float*)d_in[9];
    const float* procE  = (const float*)d_in[10];
    const float* labE   = (const float*)d_in[11];
    const float* condE  = (const float*)d_in[12];
    const float* genE   = (const float*)d_in[13];
    const float* ethE   = (const float*)d_in[14];
    const float* insE   = (const float*)d_in[15];
    const float* ageE   = (const float*)d_in[16];
    const float* projW  = (const float*)d_in[17];
    const float* projb  = (const float*)d_in[18];
    const float* W1     = (const float*)d_in[19];
    const float* b1     = (const float*)d_in[20];
    const float* W2     = (const float*)d_in[21];
    const float* b2     = (const float*)d_in[22];
    const float* fc1W   = (const float*)d_in[23];
    const float* fc1b   = (const float*)d_in[24];
    const float* fc2W   = (const float*)d_in[25];
    const float* fc2b   = (const float*)d_in[26];

    float* rm   = (float*)d_ws;                 // rm[8817]
    int*   ctr  = (int*)d_ws + OFF_CTR;         // completion counter
    float* part = (float*)d_ws + OFF_PART;      // part[435][32]
    float* outp = (float*)d_out;                // 128 floats

    // A: row means + counter reset + 8x-replicated L2 weight prefetch
    rowmeans_kernel<<<NBLKA_ROWS_ + NBLKA_PF_, NTHR_, 0, stream>>>(
        medE, chartE, outE, procE, labE, condE, genE, ethE, insE, ageE,
        projW, W1, W2, fc1W, rm, ctr);

    // B: coalesced colsum partials + last-block head (L2-warm weights)
    colsum_head_kernel<<<NBLK_B_, NTHR_, 0, stream>>>(
        meds, chart, outv, proc, lab, conds, demo, rm, part, ctr,
        projW, projb, W1, b1, W2, b2, fc1W, fc1b, fc2W, fc2b, outp);
}

// Round 6
// 38.815 us; speedup vs baseline: 1.1765x; 1.1765x over previous
//
#include <hip/hip_runtime.h>
#include <math.h>

#define B_ 64
#define S_ 24
#define E_ 128
#define G_ 256
#define N_ (B_ * S_)      // 1536
#define Km_ 100
#define Kch_ 200
#define Ko_ 50
#define Kp_ 50
#define Kc_ 30
#define TOTK_ 435         // 100+200+50+50+1+30+4

#define Vm_ 1000
#define Vch_ 3000
#define Vo_ 500
#define Vp_ 1500
#define Vl_ 700
#define Vc_ 2000
#define TOTROWS_ 8817

// ws float-offsets
#define OFF_MED 0
#define OFF_CHART 1000
#define OFF_OUT 4000
#define OFF_PROC 4500
#define OFF_LAB 6000
#define OFF_COND 6700
#define OFF_GEN 8700
#define OFF_ETH 8702
#define OFF_INS 8712
#define OFF_AGE 8717
#define OFF_FLAG 8824     // 8 ints (flags 0..5 used)
#define OFF_PART 8832     // part[435][32]
#define OFF_SM   22752    // sm[435]
#define OFF_XBAR 23200    // xbar[128]
#define OFF_H1   23328    // h1[256]
#define OFF_H2   23584    // h2[256]
#define OFF_F    23840    // f[128]

#define NCHUNK_ 32
#define CHUNK_N_ 48       // 1536/32
#define NTHR_ 512
#define NBLK_B_ 158       // 29 stage blocks + 128 table chunks + 1 small

__device__ __forceinline__ int clampi(int v, int hi) {
    return v < 0 ? 0 : (v > hi ? hi : v);
}

// ---- device-coherent (cross-XCD) helpers: no cache-invalidating acquire ----
__device__ __forceinline__ float gload(const float* p) {
    return __hip_atomic_load(p, __ATOMIC_RELAXED, __HIP_MEMORY_SCOPE_AGENT);
}
__device__ __forceinline__ void gstore(float* p, float v) {
    __hip_atomic_store(p, v, __ATOMIC_RELAXED, __HIP_MEMORY_SCOPE_AGENT);
}
__device__ __forceinline__ int flag_add(int* f) {   // release: prior stores visible first
    return __hip_atomic_fetch_add(f, 1, __ATOMIC_RELEASE, __HIP_MEMORY_SCOPE_AGENT);
}
__device__ __forceinline__ void spin_flag(int* f, int target) {
    int n = 0;
    while (__hip_atomic_load(f, __ATOMIC_RELAXED, __HIP_MEMORY_SCOPE_AGENT) < target) {
        __builtin_amdgcn_s_sleep(2);
        if (((++n) & 4095) == 0) __threadfence();   // progress guarantee; never in fast path
    }
}

// ---------------------------------------------------------------------------
// Kernel A: rowmeans (one wave per embedding row). Block 0 resets flags.
// ---------------------------------------------------------------------------
__global__ __launch_bounds__(NTHR_) void rowmeans_kernel(
    const float* __restrict__ medE, const float* __restrict__ chartE,
    const float* __restrict__ outE, const float* __restrict__ procE,
    const float* __restrict__ labE, const float* __restrict__ condE,
    const float* __restrict__ genE, const float* __restrict__ ethE,
    const float* __restrict__ insE, const float* __restrict__ ageE,
    float* __restrict__ rm, int* __restrict__ flags)
{
    if (blockIdx.x == 0 && threadIdx.x < 8) flags[threadIdx.x] = 0;

    int row = blockIdx.x * (NTHR_ / 64) + (threadIdx.x >> 6);
    int lane = threadIdx.x & 63;
    if (row >= TOTROWS_) return;

    const float* src;
    int r = row;
    if (r < Vm_)                  { src = medE; }
    else if ((r -= Vm_)  < Vch_)  { src = chartE; }
    else if ((r -= Vch_) < Vo_)   { src = outE; }
    else if ((r -= Vo_)  < Vp_)   { src = procE; }
    else if ((r -= Vp_)  < Vl_)   { src = labE; }
    else if ((r -= Vl_)  < Vc_)   { src = condE; }
    else if ((r -= Vc_)  < 2)     { src = genE; }
    else if ((r -= 2)    < 10)    { src = ethE; }
    else if ((r -= 10)   < 5)     { src = insE; }
    else                          { r -= 5; src = ageE; }

    float2 v = *reinterpret_cast<const float2*>(src + (size_t)r * E_ + lane * 2);
    float s = v.x + v.y;
    #pragma unroll
    for (int off = 32; off > 0; off >>= 1) s += __shfl_down(s, off, 64);
    if (lane == 0) rm[row] = s * (1.0f / E_);
}

// ---------------------------------------------------------------------------
// Coalesced per-table chunk colsum (unchanged math, coherent part stores)
// ---------------------------------------------------------------------------
template<int K, int RPI, int CBASE, int RMBASE, int VMAX>
__device__ __forceinline__ void table_chunk(
    const int* __restrict__ idx, const float* __restrict__ rm,
    float* __restrict__ part, int p, int t, float* __restrict__ lds)
{
    constexpr int ACT = K * RPI;
    float acc = 0.0f;
    if (t < ACT) {
        const int kk = t % K;
        const int nr = t / K;
        const int n0 = p * CHUNK_N_;
        #pragma unroll
        for (int i = 0; i < (CHUNK_N_ + RPI - 1) / RPI; ++i) {
            int n = n0 + nr + i * RPI;
            if (nr + i * RPI < CHUNK_N_) {
                int ix = clampi(idx[n * K + kk], VMAX);
                acc += rm[RMBASE + ix];
            }
        }
    }
    lds[t] = acc;
    __syncthreads();
    if (t < K) {
        float s = lds[t];
        #pragma unroll
        for (int r = 1; r < RPI; ++r) s += lds[r * K + t];
        gstore(&part[(CBASE + t) * NCHUNK_ + p], s);   // raw sum; scaled in sm stage
    }
}

// ---------------------------------------------------------------------------
// Generic pipeline GEMV stage: out[c0..c0+NC) = act(in[NI] @ W[NI][LDW] + b)
// Weight slice preloaded into REGISTERS before the spin (latency hidden under
// colsum; registers immune to cache invalidation).
// ---------------------------------------------------------------------------
template<int NC, int KG, int KPT, int NI, int LDW, int ACTM>
__device__ void stage_gemv(const float* __restrict__ W,
                           const float* __restrict__ bias,
                           const float* inbuf, float* outbuf, int c0,
                           int* flagP, int target, int* flagN)
{
    __shared__ float ins[448];
    __shared__ float red[NTHR_];

    const int t = threadIdx.x;
    const int c = t % NC;
    const int kg = t / NC;           // KG groups, KG*NC == 512
    const int kbase = kg * KPT;

    // ---- register preload (issued immediately at block start) ----
    float w[KPT];
    #pragma unroll
    for (int i = 0; i < KPT; ++i) {
        int k = kbase + i;
        w[i] = (k < NI) ? W[(size_t)k * LDW + c0 + c] : 0.f;
    }
    float bv = (t < NC) ? bias[c0 + t] : 0.f;
    float chk = bv;
    #pragma unroll
    for (int i = 0; i < KPT; ++i) chk += w[i];
    asm volatile("" :: "v"(chk));    // force loads before the spin

    if (t == 0) spin_flag(flagP, target);
    __syncthreads();

    // ---- coherent activation read into LDS ----
    for (int i = t; i < NI; i += NTHR_) ins[i] = gload(inbuf + i);
    for (int i = NI + t; i < 448; i += NTHR_) ins[i] = 0.f;
    __syncthreads();

    float part = 0.f;
    #pragma unroll
    for (int i = 0; i < KPT; ++i) part += w[i] * ins[kbase + i];
    red[t] = part;
    __syncthreads();

    if (t < NC) {
        float s = 0.f;
        #pragma unroll
        for (int g = 0; g < KG; ++g) s += red[g * NC + t];
        s += bv;
        if (ACTM == 1) s = fmaxf(s, 0.f);
        if (ACTM == 2) s = fmaxf(s, 0.f) * (1.0f / N_);
        gstore(outbuf + c0 + t, s);
    }
    __syncthreads();                 // drains stores (waitcnt before barrier)
    if (t == 0) flag_add(flagN);
}

// ---------------------------------------------------------------------------
// Final stage: o = f . fc2W + fc2b; outputs sigmoid(o) x64 then o x64.
// ---------------------------------------------------------------------------
__device__ void stage_o(const float* fbuf, const float* __restrict__ fc2W,
                        const float* __restrict__ fc2b, int* flag5,
                        float* __restrict__ outp)
{
    __shared__ float hred[8];
    __shared__ float oval;
    const int t = threadIdx.x;

    float wv = (t < 128) ? fc2W[t] : 0.f;
    float b0 = fc2b[0];
    asm volatile("" :: "v"(wv), "v"(b0));

    if (t == 0) spin_flag(flag5, 4);
    __syncthreads();

    float p = (t < 128) ? gload(fbuf + t) * wv : 0.f;
    #pragma unroll
    for (int off = 32; off > 0; off >>= 1) p += __shfl_down(p, off, 64);
    if ((t & 63) == 0) hred[t >> 6] = p;
    __syncthreads();
    if (t == 0) {
        float o = b0;
        #pragma unroll
        for (int j = 0; j < 8; ++j) o += hred[j];
        oval = o;
    }
    __syncthreads();
    const float o = oval;
    const float sig = 1.0f / (1.0f + expf(-o));
    if (t < 64)        outp[t] = sig;
    else if (t < 128)  outp[t] = o;
}

// ---------------------------------------------------------------------------
// Kernel B: 29 pipeline stage blocks (0..28) + 129 colsum blocks (29..157).
// Colsum winner computes sm[435]; stages chain via flags.
// ---------------------------------------------------------------------------
__global__ __launch_bounds__(NTHR_) void colsum_pipe_kernel(
    const int* __restrict__ meds, const int* __restrict__ chart,
    const int* __restrict__ outv, const int* __restrict__ proc,
    const int* __restrict__ lab,  const int* __restrict__ conds,
    const int* __restrict__ demo,
    const float* __restrict__ rm, float* __restrict__ part,
    int* __restrict__ flags,
    float* __restrict__ sm, float* __restrict__ xbar,
    float* __restrict__ h1, float* __restrict__ h2, float* __restrict__ f,
    const float* __restrict__ projW, const float* __restrict__ projb,
    const float* __restrict__ W1, const float* __restrict__ b1,
    const float* __restrict__ W2, const float* __restrict__ b2,
    const float* __restrict__ fc1W, const float* __restrict__ fc1b,
    const float* __restrict__ fc2W, const float* __restrict__ fc2b,
    float* __restrict__ outp)
{
    const int bid = blockIdx.x;
    const int t = threadIdx.x;

    if (bid < 8) {          // xbar[128] = sm @ projW + projb
        stage_gemv<16, 32, 14, TOTK_, 128, 0>(projW, projb, sm, xbar, bid * 16,
                                              flags + 1, 1, flags + 2);
        return;
    }
    if (bid < 16) {         // h1 = relu(xbar @ W1 + b1) * 1/N
        stage_gemv<32, 16, 8, 128, 256, 2>(W1, b1, xbar, h1, (bid - 8) * 32,
                                           flags + 2, 8, flags + 3);
        return;
    }
    if (bid < 24) {         // h2 = h1 @ W2 + b2
        stage_gemv<32, 16, 16, 256, 256, 0>(W2, b2, h1, h2, (bid - 16) * 32,
                                            flags + 3, 8, flags + 4);
        return;
    }
    if (bid < 28) {         // f = relu(h2 @ fc1W + fc1b)
        stage_gemv<32, 16, 16, 256, 128, 1>(fc1W, fc1b, h2, f, (bid - 24) * 32,
                                            flags + 4, 8, flags + 5);
        return;
    }
    if (bid == 28) {        // o + outputs
        stage_o(f, fc2W, fc2b, flags + 5, outp);
        return;
    }

    // ---- colsum blocks: bid 29..156 table chunks, 157 small columns ----
    __shared__ float lds_red[NTHR_];
    __shared__ int s_old;

    if (bid < 157) {
        const int cb = bid - 29;
        const int table = cb >> 5;
        const int p = cb & 31;
        if (table == 0)      table_chunk<Km_, 5, 0,   OFF_MED,  Vm_ -1>(meds,  rm, part, p, t, lds_red);
        else if (table == 1) table_chunk<Kch_,2, 100, OFF_CHART,Vch_-1>(chart, rm, part, p, t, lds_red);
        else if (table == 2) table_chunk<Ko_, 10,300, OFF_OUT,  Vo_ -1>(outv,  rm, part, p, t, lds_red);
        else                 table_chunk<Kp_, 10,350, OFF_PROC, Vp_ -1>(proc,  rm, part, p, t, lds_red);
    } else {
        const int lane = t & 63;
        const int w = t >> 6;
        for (int j = w; j < 35; j += 8) {
            float s = 0.0f;
            if (j == 0) {
                #pragma unroll
                for (int i = 0; i < 24; ++i)
                    s += rm[OFF_LAB + clampi(lab[lane + 64 * i], Vl_ - 1)];
            } else if (j < 31) {
                int kk = j - 1;
                s = rm[OFF_COND + clampi(conds[lane * Kc_ + kk], Vc_ - 1)];
            } else {
                int jj = j - 31;
                int base = (jj == 0) ? OFF_GEN : (jj == 1) ? OFF_ETH :
                           (jj == 2) ? OFF_INS : OFF_AGE;
                s = rm[base + demo[lane * 4 + jj]];
            }
            #pragma unroll
            for (int off = 32; off > 0; off >>= 1) s += __shfl_down(s, off, 64);
            if (lane == 0) gstore(&part[(400 + j) * NCHUNK_], s);
        }
    }

    __syncthreads();                          // drain part stores
    if (t == 0) s_old = flag_add(flags + 0);  // release
    __syncthreads();

    if (s_old == 128) {                       // last colsum block: compute sm
        if (t < TOTK_) {
            float s;
            if (t < 400) {
                s = 0.f;
                #pragma unroll
                for (int p = 0; p < NCHUNK_; ++p) s += gload(part + t * NCHUNK_ + p);
                s *= (1.0f / N_);
            } else if (t == 400) {
                s = gload(part + t * NCHUNK_) * (1.0f / N_);
            } else {
                s = gload(part + t * NCHUNK_) * (1.0f / B_);
            }
            gstore(sm + t, s);
        }
        __syncthreads();                      // drain sm stores
        if (t == 0) flag_add(flags + 1);
    }
}

// ---------------------------------------------------------------------------
extern "C" void kernel_launch(void* const* d_in, const int* in_sizes, int n_in,
                              void* d_out, int out_size, void* d_ws, size_t ws_size,
                              hipStream_t stream) {
    const int* meds  = (const int*)d_in[0];
    const int* chart = (const int*)d_in[1];
    const int* outv  = (const int*)d_in[2];
    const int* proc  = (const int*)d_in[3];
    const int* lab   = (const int*)d_in[4];
    const int* conds = (const int*)d_in[5];
    const int* demo  = (const int*)d_in[6];
    const float* medE   = (const float*)d_in[7];
    const float* chartE = (const float*)d_in[8];
    const float* outE   = (const float*)d_in[9];
    const float* procE  = (const float*)d_in[10];
    const float* labE   = (const float*)d_in[11];
    const float* condE  = (const float*)d_in[12];
    const float* genE   = (const float*)d_in[13];
    const float* ethE   = (const float*)d_in[14];
    const float* insE   = (const float*)d_in[15];
    const float* ageE   = (const float*)d_in[16];
    const float* projW  = (const float*)d_in[17];
    const float* projb  = (const float*)d_in[18];
    const float* W1     = (const float*)d_in[19];
    const float* b1     = (const float*)d_in[20];
    const float* W2     = (const float*)d_in[21];
    const float* b2     = (const float*)d_in[22];
    const float* fc1W   = (const float*)d_in[23];
    const float* fc1b   = (const float*)d_in[24];
    const float* fc2W   = (const float*)d_in[25];
    const float* fc2b   = (const float*)d_in[26];

    float* ws   = (float*)d_ws;
    float* rm   = ws;                 // rm[8817]
    int*   flags= (int*)d_ws + OFF_FLAG;
    float* part = ws + OFF_PART;      // part[435][32]
    float* sm   = ws + OFF_SM;
    float* xbar = ws + OFF_XBAR;
    float* h1   = ws + OFF_H1;
    float* h2   = ws + OFF_H2;
    float* f    = ws + OFF_F;
    float* outp = (float*)d_out;      // 128 floats

    // A: row means + flag reset
    int blocksA = (TOTROWS_ + (NTHR_ / 64) - 1) / (NTHR_ / 64);
    rowmeans_kernel<<<blocksA, NTHR_, 0, stream>>>(
        medE, chartE, outE, procE, labE, condE, genE, ethE, insE, ageE, rm, flags);

    // B: colsum + register-resident multi-block head pipeline
    colsum_pipe_kernel<<<NBLK_B_, NTHR_, 0, stream>>>(
        meds, chart, outv, proc, lab, conds, demo, rm, part, flags,
        sm, xbar, h1, h2, f,
        projW, projb, W1, b1, W2, b2, fc1W, fc1b, fc2W, fc2b, outp);
}

// Round 7
// 28.476 us; speedup vs baseline: 1.6037x; 1.3631x over previous
//
#include <hip/hip_runtime.h>
#include <math.h>

#define B_ 64
#define S_ 24
#define E_ 128
#define G_ 256
#define N_ (B_ * S_)      // 1536
#define Km_ 100
#define Kch_ 200
#define Ko_ 50
#define Kp_ 50
#define Kc_ 30
#define TOTK_ 435         // 100+200+50+50+1+30+4

#define Vm_ 1000
#define Vch_ 3000
#define Vo_ 500
#define Vp_ 1500
#define Vl_ 700
#define Vc_ 2000
#define TOTROWS_ 8817

// ws float-offsets
#define OFF_MED 0
#define OFF_CHART 1000
#define OFF_OUT 4000
#define OFF_PROC 4500
#define OFF_LAB 6000
#define OFF_COND 6700
#define OFF_GEN 8700
#define OFF_ETH 8702
#define OFF_INS 8712
#define OFF_AGE 8717
#define OFF_PART 8832     // part[435][32] floats (byte off 35328, 16B-aligned)

#define NCHUNK_ 32
#define CHUNK_N_ 48       // 1536/32
#define NBLK_B_ 129       // 128 table chunks + 1 small block
#define NTHR_ 512

__device__ __forceinline__ int clampi(int v, int hi) {
    return v < 0 ? 0 : (v > hi ? hi : v);
}

// ---------------------------------------------------------------------------
// Kernel A: one wave per embedding row -> rowmean over E=128
// ---------------------------------------------------------------------------
__global__ __launch_bounds__(NTHR_) void rowmeans_kernel(
    const float* __restrict__ medE, const float* __restrict__ chartE,
    const float* __restrict__ outE, const float* __restrict__ procE,
    const float* __restrict__ labE, const float* __restrict__ condE,
    const float* __restrict__ genE, const float* __restrict__ ethE,
    const float* __restrict__ insE, const float* __restrict__ ageE,
    float* __restrict__ rm)
{
    int row = blockIdx.x * (NTHR_ / 64) + (threadIdx.x >> 6);
    int lane = threadIdx.x & 63;
    if (row >= TOTROWS_) return;

    const float* src;
    int r = row;
    if (r < Vm_)                  { src = medE; }
    else if ((r -= Vm_)  < Vch_)  { src = chartE; }
    else if ((r -= Vch_) < Vo_)   { src = outE; }
    else if ((r -= Vo_)  < Vp_)   { src = procE; }
    else if ((r -= Vp_)  < Vl_)   { src = labE; }
    else if ((r -= Vl_)  < Vc_)   { src = condE; }
    else if ((r -= Vc_)  < 2)     { src = genE; }
    else if ((r -= 2)    < 10)    { src = ethE; }
    else if ((r -= 10)   < 5)     { src = insE; }
    else                          { r -= 5; src = ageE; }

    float2 v = *reinterpret_cast<const float2*>(src + (size_t)r * E_ + lane * 2);
    float s = v.x + v.y;
    #pragma unroll
    for (int off = 32; off > 0; off >>= 1) s += __shfl_down(s, off, 64);
    if (lane == 0) rm[row] = s * (1.0f / E_);
}

// ---------------------------------------------------------------------------
// Coalesced per-table chunk colsum: threads map to (row-in-group, column) so
// idx loads are contiguous; fully-unrolled gather chains; normal stores.
// ---------------------------------------------------------------------------
template<int K, int RPI, int CBASE, int RMBASE, int VMAX>
__device__ __forceinline__ void table_chunk(
    const int* __restrict__ idx, const float* __restrict__ rm,
    float* __restrict__ part, int p, int t, float* __restrict__ lds)
{
    constexpr int ACT = K * RPI;
    float acc = 0.0f;
    if (t < ACT) {
        const int kk = t % K;
        const int nr = t / K;
        const int n0 = p * CHUNK_N_;
        #pragma unroll
        for (int i = 0; i < (CHUNK_N_ + RPI - 1) / RPI; ++i) {
            int n = n0 + nr + i * RPI;
            if (nr + i * RPI < CHUNK_N_) {
                int ix = clampi(idx[n * K + kk], VMAX);
                acc += rm[RMBASE + ix];
            }
        }
    }
    lds[t] = acc;
    __syncthreads();
    if (t < K) {
        float s = lds[t];
        #pragma unroll
        for (int r = 1; r < RPI; ++r) s += lds[r * K + t];
        part[(CBASE + t) * NCHUNK_ + p] = s;   // raw sum; scaled in head
    }
}

// ---------------------------------------------------------------------------
// Kernel B: 129 blocks. Blocks 0..127 = (table = bid/32, chunk = bid%32);
// block 128 = lab/conds/demo via wave reductions. No atomics/fences; the
// kernel boundary publishes `part` to kernel C.
// ---------------------------------------------------------------------------
__global__ __launch_bounds__(NTHR_) void colsum_kernel(
    const int* __restrict__ meds, const int* __restrict__ chart,
    const int* __restrict__ outv, const int* __restrict__ proc,
    const int* __restrict__ lab,  const int* __restrict__ conds,
    const int* __restrict__ demo,
    const float* __restrict__ rm, float* __restrict__ part)
{
    __shared__ float lds_red[NTHR_];
    const int t = threadIdx.x;
    const int bid = blockIdx.x;

    if (bid < 128) {
        const int table = bid >> 5;
        const int p = bid & 31;
        if (table == 0)      table_chunk<Km_, 5, 0,   OFF_MED,  Vm_ -1>(meds,  rm, part, p, t, lds_red);
        else if (table == 1) table_chunk<Kch_,2, 100, OFF_CHART,Vch_-1>(chart, rm, part, p, t, lds_red);
        else if (table == 2) table_chunk<Ko_, 10,300, OFF_OUT,  Vo_ -1>(outv,  rm, part, p, t, lds_red);
        else                 table_chunk<Kp_, 10,350, OFF_PROC, Vp_ -1>(proc,  rm, part, p, t, lds_red);
    } else {
        // small block: 35 columns (lab, conds x30, demo x4), one per wave slot
        const int lane = t & 63;
        const int w = t >> 6;
        for (int j = w; j < 35; j += 8) {
            float s = 0.0f;
            if (j == 0) {
                #pragma unroll
                for (int i = 0; i < 24; ++i)
                    s += rm[OFF_LAB + clampi(lab[lane + 64 * i], Vl_ - 1)];
            } else if (j < 31) {
                int kk = j - 1;
                s = rm[OFF_COND + clampi(conds[lane * Kc_ + kk], Vc_ - 1)];
            } else {
                int jj = j - 31;
                int base = (jj == 0) ? OFF_GEN : (jj == 1) ? OFF_ETH :
                           (jj == 2) ? OFF_INS : OFF_AGE;
                s = rm[base + demo[lane * 4 + jj]];
            }
            #pragma unroll
            for (int off = 32; off > 0; off >>= 1) s += __shfl_down(s, off, 64);
            if (lane == 0) part[(400 + j) * NCHUNK_] = s;
        }
    }
}

// ---------------------------------------------------------------------------
// Kernel C: head. Sums the 32 partials per column (fixed order), scales,
// then the 4-stage MLP chain 8-way k-split with float2/float4 cached loads.
// Entropy weight over identical rows == exactly 1/N.
// ---------------------------------------------------------------------------
__global__ __launch_bounds__(NTHR_) void head_kernel(
    const float* __restrict__ part,
    const float* __restrict__ projW, const float* __restrict__ projb,
    const float* __restrict__ W1, const float* __restrict__ b1,
    const float* __restrict__ W2, const float* __restrict__ b2,
    const float* __restrict__ fc1W, const float* __restrict__ fc1b,
    const float* __restrict__ fc2W, const float* __restrict__ fc2b,
    float* __restrict__ outp)
{
    __shared__ float sm[TOTK_];
    __shared__ float xbar[E_];
    __shared__ float h1s[G_];
    __shared__ float h2s[G_];
    __shared__ float fsh[G_ / 2];
    __shared__ float4 part4[8][64];
    __shared__ float2 part2[8][64];
    __shared__ float hred[8];
    __shared__ float oval;

    const int t = threadIdx.x;
    const int lane = t & 63;
    const int oc = t >> 6;      // wave-group 0..7

    // ---- partial-sum stage: sm[k] = scale * sum_p part[k][p]
    if (t < TOTK_) {
        const float4* pp = (const float4*)(part + t * NCHUNK_);
        float s;
        if (t < 400) {
            s = 0.f;
            #pragma unroll
            for (int j = 0; j < NCHUNK_ / 4; ++j) {
                float4 v = pp[j];
                s += (v.x + v.y) + (v.z + v.w);
            }
            s *= (1.0f / N_);
        } else if (t == 400) {
            s = part[t * NCHUNK_] * (1.0f / N_);
        } else {
            s = part[t * NCHUNK_] * (1.0f / B_);
        }
        sm[t] = s;
    }
    __syncthreads();

    // ---- xbar[128] = sm[435] @ projW[435,128] + projb : float2, 8-way
    {
        const float2* Wp = (const float2*)projW;   // [435][64]
        const int k0 = (TOTK_ * oc) >> 3;
        const int k1 = (TOTK_ * (oc + 1)) >> 3;
        float2 acc = {0.f, 0.f};
        #pragma unroll 8
        for (int k = k0; k < k1; ++k) {
            float s = sm[k];
            float2 w = Wp[k * 64 + lane];
            acc.x += s * w.x; acc.y += s * w.y;
        }
        part2[oc][lane] = acc;
        __syncthreads();
        if (t < 64) {
            float2 a = part2[0][t];
            #pragma unroll
            for (int j = 1; j < 8; ++j) { a.x += part2[j][t].x; a.y += part2[j][t].y; }
            xbar[2 * t]     = a.x + projb[2 * t];
            xbar[2 * t + 1] = a.y + projb[2 * t + 1];
        }
        __syncthreads();
    }

    // ---- h1[256] = relu(xbar @ W1[128,256] + b1) * (1/N) : float4, 8-way
    {
        const float4* Wp = (const float4*)W1;      // [128][64]
        const int k0 = oc * 16, k1 = k0 + 16;
        float4 acc = {0.f, 0.f, 0.f, 0.f};
        #pragma unroll 8
        for (int k = k0; k < k1; ++k) {
            float s = xbar[k];
            float4 w = Wp[k * 64 + lane];
            acc.x += s * w.x; acc.y += s * w.y; acc.z += s * w.z; acc.w += s * w.w;
        }
        part4[oc][lane] = acc;
        __syncthreads();
        if (t < 64) {
            float4 a = part4[0][t];
            #pragma unroll
            for (int j = 1; j < 8; ++j) {
                float4 p = part4[j][t];
                a.x += p.x; a.y += p.y; a.z += p.z; a.w += p.w;
            }
            float4 bb = ((const float4*)b1)[t];
            h1s[4 * t]     = fmaxf(a.x + bb.x, 0.f) * (1.0f / N_);
            h1s[4 * t + 1] = fmaxf(a.y + bb.y, 0.f) * (1.0f / N_);
            h1s[4 * t + 2] = fmaxf(a.z + bb.z, 0.f) * (1.0f / N_);
            h1s[4 * t + 3] = fmaxf(a.w + bb.w, 0.f) * (1.0f / N_);
        }
        __syncthreads();
    }

    // ---- h2[256] = h1 @ W2[256,256] + b2 : float4, 8-way
    {
        const float4* Wp = (const float4*)W2;      // [256][64]
        const int k0 = oc * 32, k1 = k0 + 32;
        float4 acc = {0.f, 0.f, 0.f, 0.f};
        #pragma unroll 8
        for (int k = k0; k < k1; ++k) {
            float s = h1s[k];
            float4 w = Wp[k * 64 + lane];
            acc.x += s * w.x; acc.y += s * w.y; acc.z += s * w.z; acc.w += s * w.w;
        }
        part4[oc][lane] = acc;
        __syncthreads();
        if (t < 64) {
            float4 a = part4[0][t];
            #pragma unroll
            for (int j = 1; j < 8; ++j) {
                float4 p = part4[j][t];
                a.x += p.x; a.y += p.y; a.z += p.z; a.w += p.w;
            }
            float4 bb = ((const float4*)b2)[t];
            h2s[4 * t]     = a.x + bb.x;
            h2s[4 * t + 1] = a.y + bb.y;
            h2s[4 * t + 2] = a.z + bb.z;
            h2s[4 * t + 3] = a.w + bb.w;
        }
        __syncthreads();
    }

    // ---- f[128] = relu(h2 @ fc1W[256,128] + fc1b) : float2, 8-way
    {
        const float2* Wp = (const float2*)fc1W;    // [256][64]
        const int k0 = oc * 32, k1 = k0 + 32;
        float2 acc = {0.f, 0.f};
        #pragma unroll 8
        for (int k = k0; k < k1; ++k) {
            float s = h2s[k];
            float2 w = Wp[k * 64 + lane];
            acc.x += s * w.x; acc.y += s * w.y;
        }
        part2[oc][lane] = acc;
        __syncthreads();
        if (t < 64) {
            float2 a = part2[0][t];
            #pragma unroll
            for (int j = 1; j < 8; ++j) { a.x += part2[j][t].x; a.y += part2[j][t].y; }
            fsh[2 * t]     = fmaxf(a.x + fc1b[2 * t], 0.f);
            fsh[2 * t + 1] = fmaxf(a.y + fc1b[2 * t + 1], 0.f);
        }
        __syncthreads();
    }

    // ---- o = f . fc2_W + fc2_b ; write outputs
    {
        float p = (t < G_ / 2) ? fsh[t] * fc2W[t] : 0.f;
        #pragma unroll
        for (int off = 32; off > 0; off >>= 1) p += __shfl_down(p, off, 64);
        if (lane == 0) hred[oc] = p;
        __syncthreads();
        if (t == 0) {
            float o = fc2b[0];
            #pragma unroll
            for (int j = 0; j < 8; ++j) o += hred[j];
            oval = o;
        }
        __syncthreads();
        const float o = oval;
        const float sig = 1.0f / (1.0f + expf(-o));
        if (t < B_)            outp[t] = sig;   // output 0: sigmoid(o)
        else if (t < 2 * B_)   outp[t] = o;     // output 1: o
    }
}

// ---------------------------------------------------------------------------
extern "C" void kernel_launch(void* const* d_in, const int* in_sizes, int n_in,
                              void* d_out, int out_size, void* d_ws, size_t ws_size,
                              hipStream_t stream) {
    const int* meds  = (const int*)d_in[0];
    const int* chart = (const int*)d_in[1];
    const int* outv  = (const int*)d_in[2];
    const int* proc  = (const int*)d_in[3];
    const int* lab   = (const int*)d_in[4];
    const int* conds = (const int*)d_in[5];
    const int* demo  = (const int*)d_in[6];
    const float* medE   = (const float*)d_in[7];
    const float* chartE = (const float*)d_in[8];
    const float* outE   = (const float*)d_in[9];
    const float* procE  = (const float*)d_in[10];
    const float* labE   = (const float*)d_in[11];
    const float* condE  = (const float*)d_in[12];
    const float* genE   = (const float*)d_in[13];
    const float* ethE   = (const float*)d_in[14];
    const float* insE   = (const float*)d_in[15];
    const float* ageE   = (const float*)d_in[16];
    const float* projW  = (const float*)d_in[17];
    const float* projb  = (const float*)d_in[18];
    const float* W1     = (const float*)d_in[19];
    const float* b1     = (const float*)d_in[20];
    const float* W2     = (const float*)d_in[21];
    const float* b2     = (const float*)d_in[22];
    const float* fc1W   = (const float*)d_in[23];
    const float* fc1b   = (const float*)d_in[24];
    const float* fc2W   = (const float*)d_in[25];
    const float* fc2b   = (const float*)d_in[26];

    float* rm   = (float*)d_ws;                 // rm[8817]
    float* part = (float*)d_ws + OFF_PART;      // part[435][32]
    float* outp = (float*)d_out;                // 128 floats

    // A: row means
    int blocksA = (TOTROWS_ + (NTHR_ / 64) - 1) / (NTHR_ / 64);
    rowmeans_kernel<<<blocksA, NTHR_, 0, stream>>>(
        medE, chartE, outE, procE, labE, condE, genE, ethE, insE, ageE, rm);

    // B: coalesced colsum partials
    colsum_kernel<<<NBLK_B_, NTHR_, 0, stream>>>(
        meds, chart, outv, proc, lab, conds, demo, rm, part);

    // C: head (plain cached loads; L2/L3-warm across replays)
    head_kernel<<<1, NTHR_, 0, stream>>>(
        part, projW, projb, W1, b1, W2, b2, fc1W, fc1b, fc2W, fc2b, outp);
}